// Round 1
// 1274.599 us; speedup vs baseline: 1.0359x; 1.0359x over previous
//
#include <hip/hip_runtime.h>
#include <stdint.h>

#define NN 20000
#define NE 80000
#define DD 1024

typedef __bf16 bf16x8 __attribute__((ext_vector_type(8)));
typedef float f32x4 __attribute__((ext_vector_type(4)));
typedef unsigned short u16;
typedef unsigned int u32;

__device__ __forceinline__ float bf2f(u16 v) { return __uint_as_float(((u32)v) << 16); }
__device__ __forceinline__ u16 f2bf(float f) { return (u16)((__float_as_uint(f) + 0x8000u) >> 16); }

// async 16B global->LDS DMA; LDS dest = wave-uniform base + lane*16
__device__ __forceinline__ void lds_dma16(const u16* g, u16* l) {
  __builtin_amdgcn_global_load_lds((const __attribute__((address_space(1))) u32*)g,
                                   (__attribute__((address_space(3))) u32*)l, 16, 0, 0);
}

// edge_index may be int64 (stride 2 in int32 words) or int32 (stride 1)
__global__ void detect_stride_k(const int* __restrict__ ei, int* flag) {
  if (threadIdx.x == 0) {
    int nz = 0;
    for (int i = 1; i < 128; i += 2) nz |= ei[i];
    *flag = (nz == 0) ? 2 : 1;
  }
}

// fp32 [1024,1024] row-major -> bf16 transposed [n][k]
__global__ void transpose_cvt_k(const float* __restrict__ in, u16* __restrict__ out) {
  __shared__ float tile[32][33];
  int bx = blockIdx.x * 32, by = blockIdx.y * 32;
  int tx = threadIdx.x & 31, ty = threadIdx.x >> 5;
#pragma unroll
  for (int s = 0; s < 4; s++)
    tile[ty + s * 8][tx] = in[(size_t)(by + ty + s * 8) * DD + bx + tx];
  __syncthreads();
#pragma unroll
  for (int s = 0; s < 4; s++)
    out[(size_t)(bx + ty + s * 8) * DD + by + tx] = f2bf(tile[tx][ty + s * 8]);
}

__global__ void cvt_bf16_k(const float4* __restrict__ in, ushort4* __restrict__ out, int n4) {
  int i = blockIdx.x * 256 + threadIdx.x;
  if (i < n4) {
    float4 f = in[i];
    ushort4 o;
    o.x = f2bf(f.x); o.y = f2bf(f.y); o.z = f2bf(f.z); o.w = f2bf(f.w);
    out[i] = o;
  }
}

__global__ void count_edges_k(const int* __restrict__ ei, const int* __restrict__ sflag,
                              int* __restrict__ cnt) {
  int e = blockIdx.x * 256 + threadIdx.x;
  if (e < NE) {
    int s = *sflag;
    atomicAdd(&cnt[ei[(size_t)s * (NE + e)]], 1);
  }
}

// single block, 1024 threads: exclusive prefix sum of cnt -> rowptr, ofs
__global__ __launch_bounds__(1024) void scan_k(const int* __restrict__ cnt,
                                               int* __restrict__ rowptr, int* __restrict__ ofs) {
  __shared__ int part[1024];
  int t = threadIdx.x;
  int base = t * 20;
  int loc[20];
  int s = 0;
#pragma unroll
  for (int i = 0; i < 20; i++) {
    int v = (base + i < NN) ? cnt[base + i] : 0;
    loc[i] = s; s += v;
  }
  part[t] = s;
  __syncthreads();
  for (int d = 1; d < 1024; d <<= 1) {
    int v = (t >= d) ? part[t - d] : 0;
    __syncthreads();
    part[t] += v;
    __syncthreads();
  }
  int excl = (t > 0) ? part[t - 1] : 0;
#pragma unroll
  for (int i = 0; i < 20; i++)
    if (base + i < NN) { rowptr[base + i] = excl + loc[i]; ofs[base + i] = excl + loc[i]; }
  if (t == 1023) rowptr[NN] = part[1023];
}

__global__ void scatter_k(const int* __restrict__ ei, const int* __restrict__ sflag,
                          int* __restrict__ ofs, int* __restrict__ perm) {
  int e = blockIdx.x * 256 + threadIdx.x;
  if (e < NE) {
    int s = *sflag;
    int c = ei[(size_t)s * (NE + e)];
    perm[atomicAdd(&ofs[c], 1)] = e;
  }
}

// mean over each node's edges of h (bf16 [E,1024]) -> sbar (bf16 [N,1024])
__global__ void seg_mean_k(const u16* __restrict__ h, const int* __restrict__ rowptr,
                           const int* __restrict__ perm, u16* __restrict__ sbar) {
  int n = blockIdx.x, t = threadIdx.x;
  int beg = rowptr[n], end = rowptr[n + 1];
  float a0 = 0, a1 = 0, a2 = 0, a3 = 0;
  for (int i = beg; i < end; i++) {
    int e = perm[i];
    ushort4 v = *(const ushort4*)(h + (size_t)e * DD + t * 4);
    a0 += bf2f(v.x); a1 += bf2f(v.y); a2 += bf2f(v.z); a3 += bf2f(v.w);
  }
  float inv = (end > beg) ? 1.0f / (float)(end - beg) : 0.0f;
  ushort4 o;
  o.x = f2bf(a0 * inv); o.y = f2bf(a1 * inv); o.z = f2bf(a2 * inv); o.w = f2bf(a3 * inv);
  *(ushort4*)(sbar + (size_t)n * DD + t * 4) = o;
}

// C[M,1024] = A(bf16 [m][k]) @ B^T(bf16 [n][k]); all operands DMA-staged.
// Double-buffered LDS, issue-early prefetch (stage t+1 before compute t),
// single barrier per K-step (syncthreads' forced vmcnt(0)+lgkmcnt(0) drain
// provides the cross-wave DMA-completion guarantee).
// 1-D grid with XCD chunk swizzle: all 8 n-blocks of an m-panel -> same XCD.
// LDS layout: 16B chunk (row,kc) at chunk index row*4 + (kc ^ ((row>>1)&3)).
// EPI 0: Cout(f32) = acc + bias
// EPI 1: Hout(bf16)[e] = relu(acc + P[row[e]])   (edge GEMM)
// EPI 2: Cbf = acc + (cnt>0 ? bias : 0)
// EPI 3: Cbf = relu(acc + bias)
// EPI 4: Cbf = acc + bias
template <int EPI, int NSRC>
__global__ __launch_bounds__(256) void gemm_k(
    const u16* __restrict__ A0, const u16* __restrict__ A1,
    const u16* __restrict__ B0, const u16* __restrict__ B1, int M,
    const float* __restrict__ bias, float* __restrict__ Cout, u16* __restrict__ Cbf,
    const u16* __restrict__ Pg, u16* __restrict__ Hout,
    const int* __restrict__ eidx, const int* __restrict__ sflag,
    const int* __restrict__ cnt) {
  __shared__ __align__(16) u16 As[2][128 * 32];
  __shared__ __align__(16) u16 Bs[2][128 * 32];

  const int tid = threadIdx.x;
  const int lane = tid & 63;
  const int wv = tid >> 6;
  const int wm = wv >> 1, wn = wv & 1;  // 2x2 waves, 64x64 each

  // XCD chunk swizzle (bijective: gridDim.x % 8 == 0 always, n-dim is 8)
  const int nwg = gridDim.x;
  const int cpx = nwg >> 3;
  const int bid = blockIdx.x;
  const int l = (bid & 7) * cpx + (bid >> 3);
  const int nblk = l & 7, mblk = l >> 3;

  const int lrow = lane & 15, kq = lane >> 4;

  int ss = 1;
  if constexpr (EPI == 1) ss = *sflag;

  // DMA staging precompute: segment s = wv*2+r covers chunks s*64..s*64+63
  size_t a_goff[2], b_goff[2];
  int lseg[2];
#pragma unroll
  for (int r = 0; r < 2; r++) {
    int p = (wv * 2 + r) * 64 + lane;
    int row = p >> 2, c = p & 3;
    int kc = c ^ ((row >> 1) & 3);
    a_goff[r] = (size_t)min(mblk * 128 + row, M - 1) * DD + kc * 8;
    b_goff[r] = (size_t)(nblk * 128 + row) * DD + kc * 8;
    lseg[r] = (wv * 2 + r) * 512;
  }

  // fragment LDS offsets (u16 units)
  int a_fo[4], b_fo[4];
#pragma unroll
  for (int i = 0; i < 4; i++) {
    int m = wm * 64 + i * 16 + lrow;
    a_fo[i] = (m * 4 + (kq ^ ((m >> 1) & 3))) * 8;
    int n = wn * 64 + i * 16 + lrow;
    b_fo[i] = (n * 4 + (kq ^ ((n >> 1) & 3))) * 8;
  }

  f32x4 acc[4][4] = {};

  const int NK = NSRC * (DD / 32);

  auto stage = [&](int b, int step) {
    const u16* Ag = A0;
    const u16* Bg = B0;
    if constexpr (NSRC == 2) {
      if (step >= DD / 32) { Ag = A1; Bg = B1; }
    }
    size_t ko = (size_t)(step & (DD / 32 - 1)) * 32;
#pragma unroll
    for (int r = 0; r < 2; r++) {
      lds_dma16(Ag + a_goff[r] + ko, &As[b][lseg[r]]);
      lds_dma16(Bg + b_goff[r] + ko, &Bs[b][lseg[r]]);
    }
  };

  // prologue: stage step 0
  stage(0, 0);
  __syncthreads();  // full vmcnt+lgkm drain -> buf0 valid for everyone

  int cur = 0;
  for (int step = 0; step < NK; step++) {
    // issue next tile's DMA BEFORE compute: latency hides under ds_read+MFMA
    if (step + 1 < NK) stage(cur ^ 1, step + 1);
    bf16x8 af[4], bf[4];
#pragma unroll
    for (int i = 0; i < 4; i++) {
      af[i] = *(const bf16x8*)&As[cur][a_fo[i]];
      bf[i] = *(const bf16x8*)&Bs[cur][b_fo[i]];
    }
#pragma unroll
    for (int i = 0; i < 4; i++)
#pragma unroll
      for (int j = 0; j < 4; j++)
        acc[i][j] = __builtin_amdgcn_mfma_f32_16x16x32_bf16(af[i], bf[j], acc[i][j], 0, 0, 0);
    // one barrier per step: drains this wave's ds_reads (lgkm) and its
    // next-tile DMAs (vmcnt); after it, everyone may read buf[cur^1] and
    // overwrite buf[cur].
    __syncthreads();
    cur ^= 1;
  }

  // epilogue: C/D layout col=lane&15, row=(lane>>4)*4+reg
#pragma unroll
  for (int i = 0; i < 4; i++) {
#pragma unroll
    for (int r = 0; r < 4; r++) {
      int grow = mblk * 128 + wm * 64 + i * 16 + kq * 4 + r;
      if (grow >= M) continue;
      int erow = 0;
      if constexpr (EPI == 1) erow = eidx[(size_t)ss * grow];
#pragma unroll
      for (int j = 0; j < 4; j++) {
        int gcol = nblk * 128 + wn * 64 + j * 16 + lrow;
        float v = acc[i][j][r];
        if constexpr (EPI == 0) {
          Cout[(size_t)grow * DD + gcol] = v + bias[gcol];
        } else if constexpr (EPI == 1) {
          float z = fmaxf(v + bf2f(Pg[(size_t)erow * DD + gcol]), 0.0f);
          Hout[(size_t)grow * DD + gcol] = f2bf(z);
        } else if constexpr (EPI == 2) {
          float b = (cnt[grow] > 0) ? bias[gcol] : 0.0f;
          Cbf[(size_t)grow * DD + gcol] = f2bf(v + b);
        } else if constexpr (EPI == 3) {
          Cbf[(size_t)grow * DD + gcol] = f2bf(fmaxf(v + bias[gcol], 0.0f));
        } else {
          Cbf[(size_t)grow * DD + gcol] = f2bf(v + bias[gcol]);
        }
      }
    }
  }
}

extern "C" void kernel_launch(void* const* d_in, const int* in_sizes, int n_in,
                              void* d_out, int out_size, void* d_ws, size_t ws_size,
                              hipStream_t stream) {
  const float* x   = (const float*)d_in[0];
  const int*   ei  = (const int*)d_in[1];
  const float* ea  = (const float*)d_in[2];
  const float* W1a = (const float*)d_in[3];
  const float* b1a = (const float*)d_in[4];
  const float* W1b = (const float*)d_in[5];
  const float* b1b = (const float*)d_in[6];
  const float* W2a = (const float*)d_in[7];
  const float* b2a = (const float*)d_in[8];
  const float* W2b = (const float*)d_in[9];
  const float* b2b = (const float*)d_in[10];
  float* out = (float*)d_out;

  char* ws = (char*)d_ws;
  size_t off = 0;
  const size_t WSZ = (size_t)DD * DD;
  u16* W1aT_t = (u16*)(ws + off); off += WSZ * 2;
  u16* W1aT_b = (u16*)(ws + off); off += WSZ * 2;
  u16* W1bT   = (u16*)(ws + off); off += WSZ * 2;
  u16* W2aT_t = (u16*)(ws + off); off += WSZ * 2;
  u16* W2aT_b = (u16*)(ws + off); off += WSZ * 2;
  u16* W2bT   = (u16*)(ws + off); off += WSZ * 2;
  u16* xb   = (u16*)(ws + off); off += (size_t)NN * DD * 2;
  u16* eb   = (u16*)(ws + off); off += (size_t)NE * DD * 2;  // ea in bf16
  u16* bufP = (u16*)(ws + off); off += (size_t)NN * DD * 2;  // P -> Sbar -> out2
  u16* bufM = (u16*)(ws + off); off += (size_t)NN * DD * 2;  // M
  u16* h    = (u16*)(ws + off); off += (size_t)NE * DD * 2;
  int* cnt    = (int*)(ws + off); off += (size_t)NN * 4;
  int* rowptr = (int*)(ws + off); off += (size_t)(NN + 1) * 4;
  int* ofs    = (int*)(ws + off); off += (size_t)NN * 4;
  int* perm   = (int*)(ws + off); off += (size_t)NE * 4;
  int* sflag  = (int*)(ws + off); off += 256;
  if (ws_size < off) return;

  dim3 tb(256);
  dim3 tg(32, 32);
  transpose_cvt_k<<<tg, tb, 0, stream>>>(W1a, W1aT_t);
  transpose_cvt_k<<<tg, tb, 0, stream>>>(W1a + WSZ, W1aT_b);
  transpose_cvt_k<<<tg, tb, 0, stream>>>(W1b, W1bT);
  transpose_cvt_k<<<tg, tb, 0, stream>>>(W2a, W2aT_t);
  transpose_cvt_k<<<tg, tb, 0, stream>>>(W2a + WSZ, W2aT_b);
  transpose_cvt_k<<<tg, tb, 0, stream>>>(W2b, W2bT);

  cvt_bf16_k<<<NN * DD / 4 / 256, tb, 0, stream>>>((const float4*)x, (ushort4*)xb, NN * DD / 4);
  cvt_bf16_k<<<NE * DD / 4 / 256, tb, 0, stream>>>((const float4*)ea, (ushort4*)eb, NE * DD / 4);

  detect_stride_k<<<1, 64, 0, stream>>>(ei, sflag);
  hipMemsetAsync(cnt, 0, (size_t)NN * 4, stream);
  count_edges_k<<<(NE + 255) / 256, tb, 0, stream>>>(ei, sflag, cnt);
  scan_k<<<1, 1024, 0, stream>>>(cnt, rowptr, ofs);
  scatter_k<<<(NE + 255) / 256, tb, 0, stream>>>(ei, sflag, ofs, perm);

  const int nmbN = (NN + 127) / 128;  // 157
  const int nmbE = NE / 128;          // 625
  dim3 gN(8 * nmbN);
  dim3 gE(8 * nmbE);

  // G1: P = xb @ W1a_top + b1a -> bufP (bf16)
  gemm_k<4, 1><<<gN, tb, 0, stream>>>(xb, nullptr, W1aT_t, nullptr, NN,
                                      b1a, nullptr, bufP, nullptr, nullptr,
                                      nullptr, nullptr, nullptr);
  // G2: h = relu(eb @ W1a_bot + P[row]) -> h (bf16)
  gemm_k<1, 1><<<gE, tb, 0, stream>>>(eb, nullptr, W1aT_b, nullptr, NE,
                                      nullptr, nullptr, nullptr, bufP, h,
                                      ei, sflag, nullptr);
  // Sbar = segment-mean of h -> bufP (P dead)
  seg_mean_k<<<NN, tb, 0, stream>>>(h, rowptr, perm, bufP);
  // G3: M = Sbar @ W1b + mask*b1b -> bufM (bf16)
  gemm_k<2, 1><<<gN, tb, 0, stream>>>(bufP, nullptr, W1bT, nullptr, NN,
                                      b1b, nullptr, bufM, nullptr, nullptr,
                                      nullptr, nullptr, cnt);
  // G4: out2 = relu(xb@W2a_top + M@W2a_bot + b2a) -> bufP (Sbar dead)
  gemm_k<3, 2><<<gN, tb, 0, stream>>>(xb, bufM, W2aT_t, W2aT_b, NN,
                                      b2a, nullptr, bufP, nullptr, nullptr,
                                      nullptr, nullptr, nullptr);
  // G5: out = out2 @ W2b + b2b -> d_out (fp32)
  gemm_k<0, 1><<<gN, tb, 0, stream>>>(bufP, nullptr, W2bT, nullptr, NN,
                                      b2b, out, nullptr, nullptr, nullptr,
                                      nullptr, nullptr, nullptr);
}

// Round 2
// 1225.755 us; speedup vs baseline: 1.0772x; 1.0398x over previous
//
#include <hip/hip_runtime.h>
#include <stdint.h>

#define NN 20000
#define NE 80000
#define DD 1024

typedef __bf16 bf16x8 __attribute__((ext_vector_type(8)));
typedef float f32x4 __attribute__((ext_vector_type(4)));
typedef unsigned short u16;
typedef unsigned int u32;

__device__ __forceinline__ float bf2f(u16 v) { return __uint_as_float(((u32)v) << 16); }
__device__ __forceinline__ u16 f2bf(float f) { return (u16)((__float_as_uint(f) + 0x8000u) >> 16); }

// async 16B global->LDS DMA; LDS dest = wave-uniform base + lane*16
__device__ __forceinline__ void lds_dma16(const u16* g, u16* l) {
  __builtin_amdgcn_global_load_lds((const __attribute__((address_space(1))) u32*)g,
                                   (__attribute__((address_space(3))) u32*)l, 16, 0, 0);
}

// edge_index may be int64 (stride 2 in int32 words) or int32 (stride 1)
__global__ void detect_stride_k(const int* __restrict__ ei, int* flag) {
  if (threadIdx.x == 0) {
    int nz = 0;
    for (int i = 1; i < 128; i += 2) nz |= ei[i];
    *flag = (nz == 0) ? 2 : 1;
  }
}

// fp32 [1024,1024] row-major -> bf16 transposed [n][k]
__global__ void transpose_cvt_k(const float* __restrict__ in, u16* __restrict__ out) {
  __shared__ float tile[32][33];
  int bx = blockIdx.x * 32, by = blockIdx.y * 32;
  int tx = threadIdx.x & 31, ty = threadIdx.x >> 5;
#pragma unroll
  for (int s = 0; s < 4; s++)
    tile[ty + s * 8][tx] = in[(size_t)(by + ty + s * 8) * DD + bx + tx];
  __syncthreads();
#pragma unroll
  for (int s = 0; s < 4; s++)
    out[(size_t)(bx + ty + s * 8) * DD + by + tx] = f2bf(tile[tx][ty + s * 8]);
}

__global__ void cvt_bf16_k(const float4* __restrict__ in, ushort4* __restrict__ out, int n4) {
  int i = blockIdx.x * 256 + threadIdx.x;
  if (i < n4) {
    float4 f = in[i];
    ushort4 o;
    o.x = f2bf(f.x); o.y = f2bf(f.y); o.z = f2bf(f.z); o.w = f2bf(f.w);
    out[i] = o;
  }
}

__global__ void count_edges_k(const int* __restrict__ ei, const int* __restrict__ sflag,
                              int* __restrict__ cnt) {
  int e = blockIdx.x * 256 + threadIdx.x;
  if (e < NE) {
    int s = *sflag;
    atomicAdd(&cnt[ei[(size_t)s * (NE + e)]], 1);
  }
}

// single block, 1024 threads: exclusive prefix sum of cnt -> rowptr, ofs
__global__ __launch_bounds__(1024) void scan_k(const int* __restrict__ cnt,
                                               int* __restrict__ rowptr, int* __restrict__ ofs) {
  __shared__ int part[1024];
  int t = threadIdx.x;
  int base = t * 20;
  int loc[20];
  int s = 0;
#pragma unroll
  for (int i = 0; i < 20; i++) {
    int v = (base + i < NN) ? cnt[base + i] : 0;
    loc[i] = s; s += v;
  }
  part[t] = s;
  __syncthreads();
  for (int d = 1; d < 1024; d <<= 1) {
    int v = (t >= d) ? part[t - d] : 0;
    __syncthreads();
    part[t] += v;
    __syncthreads();
  }
  int excl = (t > 0) ? part[t - 1] : 0;
#pragma unroll
  for (int i = 0; i < 20; i++)
    if (base + i < NN) { rowptr[base + i] = excl + loc[i]; ofs[base + i] = excl + loc[i]; }
  if (t == 1023) rowptr[NN] = part[1023];
}

__global__ void scatter_k(const int* __restrict__ ei, const int* __restrict__ sflag,
                          int* __restrict__ ofs, int* __restrict__ perm) {
  int e = blockIdx.x * 256 + threadIdx.x;
  if (e < NE) {
    int s = *sflag;
    int c = ei[(size_t)s * (NE + e)];
    perm[atomicAdd(&ofs[c], 1)] = e;
  }
}

// mean over each node's edges of h (bf16 [E,1024]) -> sbar (bf16 [N,1024])
__global__ void seg_mean_k(const u16* __restrict__ h, const int* __restrict__ rowptr,
                           const int* __restrict__ perm, u16* __restrict__ sbar) {
  int n = blockIdx.x, t = threadIdx.x;
  int beg = rowptr[n], end = rowptr[n + 1];
  float a0 = 0, a1 = 0, a2 = 0, a3 = 0;
  for (int i = beg; i < end; i++) {
    int e = perm[i];
    ushort4 v = *(const ushort4*)(h + (size_t)e * DD + t * 4);
    a0 += bf2f(v.x); a1 += bf2f(v.y); a2 += bf2f(v.z); a3 += bf2f(v.w);
  }
  float inv = (end > beg) ? 1.0f / (float)(end - beg) : 0.0f;
  ushort4 o;
  o.x = f2bf(a0 * inv); o.y = f2bf(a1 * inv); o.z = f2bf(a2 * inv); o.w = f2bf(a3 * inv);
  *(ushort4*)(sbar + (size_t)n * DD + t * 4) = o;
}

// C[M,1024] = A(bf16 [m][k]) @ B^T(bf16 [n][k]); all operands DMA-staged.
// Depth-3 software pipeline: 3 LDS buffers, counted s_waitcnt vmcnt(8) (never
// 0 in steady state), raw s_barrier (no vmcnt(0) drain), stage tile t+3 at end
// of step t -> each tile's DMAs fly across ~2 full compute steps.
// Barrier count is uniform across all waves. Compiler-only memory fences pin
// plain LDS frag-reads to their side of each raw barrier.
// 1-D grid with XCD chunk swizzle: all 8 n-blocks of an m-panel -> same XCD.
// LDS layout: 16B chunk (row,kc) at chunk index row*4 + (kc ^ ((row>>1)&3)).
// EPI 0: Cout(f32) = acc + bias
// EPI 1: Hout(bf16)[e] = relu(acc + P[row[e]])   (edge GEMM)
// EPI 2: Cbf = acc + (cnt>0 ? bias : 0)
// EPI 3: Cbf = relu(acc + bias)
// EPI 4: Cbf = acc + bias
template <int EPI, int NSRC>
__global__ __launch_bounds__(256, 3) void gemm_k(
    const u16* __restrict__ A0, const u16* __restrict__ A1,
    const u16* __restrict__ B0, const u16* __restrict__ B1, int M,
    const float* __restrict__ bias, float* __restrict__ Cout, u16* __restrict__ Cbf,
    const u16* __restrict__ Pg, u16* __restrict__ Hout,
    const int* __restrict__ eidx, const int* __restrict__ sflag,
    const int* __restrict__ cnt) {
  __shared__ __align__(16) u16 As[3][128 * 32];
  __shared__ __align__(16) u16 Bs[3][128 * 32];

  const int tid = threadIdx.x;
  const int lane = tid & 63;
  const int wv = tid >> 6;
  const int wm = wv >> 1, wn = wv & 1;  // 2x2 waves, 64x64 each

  // XCD chunk swizzle (bijective: gridDim.x % 8 == 0 always, n-dim is 8)
  const int nwg = gridDim.x;
  const int cpx = nwg >> 3;
  const int bid = blockIdx.x;
  const int l = (bid & 7) * cpx + (bid >> 3);
  const int nblk = l & 7, mblk = l >> 3;

  const int lrow = lane & 15, kq = lane >> 4;

  int ss = 1;
  if constexpr (EPI == 1) {
    ss = *sflag;
    // drain: this load must NOT be outstanding during the counted-vmcnt loop
    asm volatile("s_waitcnt vmcnt(0)" ::: "memory");
  }

  // DMA staging precompute: segment s = wv*2+r covers chunks s*64..s*64+63
  size_t a_goff[2], b_goff[2];
  int lseg[2];
#pragma unroll
  for (int r = 0; r < 2; r++) {
    int p = (wv * 2 + r) * 64 + lane;
    int row = p >> 2, c = p & 3;
    int kc = c ^ ((row >> 1) & 3);
    a_goff[r] = (size_t)min(mblk * 128 + row, M - 1) * DD + kc * 8;
    b_goff[r] = (size_t)(nblk * 128 + row) * DD + kc * 8;
    lseg[r] = (wv * 2 + r) * 512;
  }

  // fragment LDS offsets (u16 units)
  int a_fo[4], b_fo[4];
#pragma unroll
  for (int i = 0; i < 4; i++) {
    int m = wm * 64 + i * 16 + lrow;
    a_fo[i] = (m * 4 + (kq ^ ((m >> 1) & 3))) * 8;
    int n = wn * 64 + i * 16 + lrow;
    b_fo[i] = (n * 4 + (kq ^ ((n >> 1) & 3))) * 8;
  }

  f32x4 acc[4][4] = {};

  const int NK = NSRC * (DD / 32);

  auto stage = [&](int b, int step) {
    const u16* Ag = A0;
    const u16* Bg = B0;
    if constexpr (NSRC == 2) {
      if (step >= DD / 32) { Ag = A1; Bg = B1; }
    }
    size_t ko = (size_t)(step & (DD / 32 - 1)) * 32;
#pragma unroll
    for (int r = 0; r < 2; r++) {
      lds_dma16(Ag + a_goff[r] + ko, &As[b][lseg[r]]);
      lds_dma16(Bg + b_goff[r] + ko, &Bs[b][lseg[r]]);
    }
  };

  auto compute = [&](int cb) {
    bf16x8 af[4], bf[4];
#pragma unroll
    for (int i = 0; i < 4; i++) {
      af[i] = *(const bf16x8*)&As[cb][a_fo[i]];
      bf[i] = *(const bf16x8*)&Bs[cb][b_fo[i]];
    }
    __builtin_amdgcn_s_setprio(1);
#pragma unroll
    for (int i = 0; i < 4; i++)
#pragma unroll
      for (int j = 0; j < 4; j++)
        acc[i][j] = __builtin_amdgcn_mfma_f32_16x16x32_bf16(af[i], bf[j], acc[i][j], 0, 0, 0);
    __builtin_amdgcn_s_setprio(0);
  };

  // prologue: stage tiles 0,1,2 into buffers 0,1,2 (12 DMAs/wave in flight)
  stage(0, 0);
  stage(1, 1);
  stage(2, 2);

  int cur = 0;
  // main loop: t = 0 .. NK-4; tile t is in buffer cur == t%3
  for (int t = 0; t + 3 < NK; ++t) {
    // allow tiles t+1,t+2 (8 DMAs/wave) to stay in flight; tile t must be done
    asm volatile("s_waitcnt vmcnt(8)" ::: "memory");
    __builtin_amdgcn_s_barrier();  // all waves' tile-t DMAs landed
    asm volatile("" ::: "memory");
    compute(cur);
    asm volatile("" ::: "memory");
    __builtin_amdgcn_s_barrier();  // all waves done reading buffer cur
    stage(cur, t + 3);             // refill same buffer with tile t+3
    cur = (cur == 2) ? 0 : cur + 1;
  }
  // tail: tiles NK-3, NK-2, NK-1 (no more staging); drain 8 -> 4 -> 0
  asm volatile("s_waitcnt vmcnt(8)" ::: "memory");
  __builtin_amdgcn_s_barrier();
  asm volatile("" ::: "memory");
  compute(cur);
  cur = (cur == 2) ? 0 : cur + 1;
  asm volatile("s_waitcnt vmcnt(4)" ::: "memory");
  __builtin_amdgcn_s_barrier();
  asm volatile("" ::: "memory");
  compute(cur);
  cur = (cur == 2) ? 0 : cur + 1;
  asm volatile("s_waitcnt vmcnt(0)" ::: "memory");
  __builtin_amdgcn_s_barrier();
  asm volatile("" ::: "memory");
  compute(cur);

  // epilogue: C/D layout col=lane&15, row=(lane>>4)*4+reg
#pragma unroll
  for (int i = 0; i < 4; i++) {
#pragma unroll
    for (int r = 0; r < 4; r++) {
      int grow = mblk * 128 + wm * 64 + i * 16 + kq * 4 + r;
      if (grow >= M) continue;
      int erow = 0;
      if constexpr (EPI == 1) erow = eidx[(size_t)ss * grow];
#pragma unroll
      for (int j = 0; j < 4; j++) {
        int gcol = nblk * 128 + wn * 64 + j * 16 + lrow;
        float v = acc[i][j][r];
        if constexpr (EPI == 0) {
          Cout[(size_t)grow * DD + gcol] = v + bias[gcol];
        } else if constexpr (EPI == 1) {
          float z = fmaxf(v + bf2f(Pg[(size_t)erow * DD + gcol]), 0.0f);
          Hout[(size_t)grow * DD + gcol] = f2bf(z);
        } else if constexpr (EPI == 2) {
          float b = (cnt[grow] > 0) ? bias[gcol] : 0.0f;
          Cbf[(size_t)grow * DD + gcol] = f2bf(v + b);
        } else if constexpr (EPI == 3) {
          Cbf[(size_t)grow * DD + gcol] = f2bf(fmaxf(v + bias[gcol], 0.0f));
        } else {
          Cbf[(size_t)grow * DD + gcol] = f2bf(v + bias[gcol]);
        }
      }
    }
  }
}

extern "C" void kernel_launch(void* const* d_in, const int* in_sizes, int n_in,
                              void* d_out, int out_size, void* d_ws, size_t ws_size,
                              hipStream_t stream) {
  const float* x   = (const float*)d_in[0];
  const int*   ei  = (const int*)d_in[1];
  const float* ea  = (const float*)d_in[2];
  const float* W1a = (const float*)d_in[3];
  const float* b1a = (const float*)d_in[4];
  const float* W1b = (const float*)d_in[5];
  const float* b1b = (const float*)d_in[6];
  const float* W2a = (const float*)d_in[7];
  const float* b2a = (const float*)d_in[8];
  const float* W2b = (const float*)d_in[9];
  const float* b2b = (const float*)d_in[10];
  float* out = (float*)d_out;

  char* ws = (char*)d_ws;
  size_t off = 0;
  const size_t WSZ = (size_t)DD * DD;
  u16* W1aT_t = (u16*)(ws + off); off += WSZ * 2;
  u16* W1aT_b = (u16*)(ws + off); off += WSZ * 2;
  u16* W1bT   = (u16*)(ws + off); off += WSZ * 2;
  u16* W2aT_t = (u16*)(ws + off); off += WSZ * 2;
  u16* W2aT_b = (u16*)(ws + off); off += WSZ * 2;
  u16* W2bT   = (u16*)(ws + off); off += WSZ * 2;
  u16* xb   = (u16*)(ws + off); off += (size_t)NN * DD * 2;
  u16* eb   = (u16*)(ws + off); off += (size_t)NE * DD * 2;  // ea in bf16
  u16* bufP = (u16*)(ws + off); off += (size_t)NN * DD * 2;  // P -> Sbar -> out2
  u16* bufM = (u16*)(ws + off); off += (size_t)NN * DD * 2;  // M
  u16* h    = (u16*)(ws + off); off += (size_t)NE * DD * 2;
  int* cnt    = (int*)(ws + off); off += (size_t)NN * 4;
  int* rowptr = (int*)(ws + off); off += (size_t)(NN + 1) * 4;
  int* ofs    = (int*)(ws + off); off += (size_t)NN * 4;
  int* perm   = (int*)(ws + off); off += (size_t)NE * 4;
  int* sflag  = (int*)(ws + off); off += 256;
  if (ws_size < off) return;

  dim3 tb(256);
  dim3 tg(32, 32);
  transpose_cvt_k<<<tg, tb, 0, stream>>>(W1a, W1aT_t);
  transpose_cvt_k<<<tg, tb, 0, stream>>>(W1a + WSZ, W1aT_b);
  transpose_cvt_k<<<tg, tb, 0, stream>>>(W1b, W1bT);
  transpose_cvt_k<<<tg, tb, 0, stream>>>(W2a, W2aT_t);
  transpose_cvt_k<<<tg, tb, 0, stream>>>(W2a + WSZ, W2aT_b);
  transpose_cvt_k<<<tg, tb, 0, stream>>>(W2b, W2bT);

  cvt_bf16_k<<<NN * DD / 4 / 256, tb, 0, stream>>>((const float4*)x, (ushort4*)xb, NN * DD / 4);
  cvt_bf16_k<<<NE * DD / 4 / 256, tb, 0, stream>>>((const float4*)ea, (ushort4*)eb, NE * DD / 4);

  detect_stride_k<<<1, 64, 0, stream>>>(ei, sflag);
  hipMemsetAsync(cnt, 0, (size_t)NN * 4, stream);
  count_edges_k<<<(NE + 255) / 256, tb, 0, stream>>>(ei, sflag, cnt);
  scan_k<<<1, 1024, 0, stream>>>(cnt, rowptr, ofs);
  scatter_k<<<(NE + 255) / 256, tb, 0, stream>>>(ei, sflag, ofs, perm);

  const int nmbN = (NN + 127) / 128;  // 157
  const int nmbE = NE / 128;          // 625
  dim3 gN(8 * nmbN);
  dim3 gE(8 * nmbE);

  // G1: P = xb @ W1a_top + b1a -> bufP (bf16)
  gemm_k<4, 1><<<gN, tb, 0, stream>>>(xb, nullptr, W1aT_t, nullptr, NN,
                                      b1a, nullptr, bufP, nullptr, nullptr,
                                      nullptr, nullptr, nullptr);
  // G2: h = relu(eb @ W1a_bot + P[row]) -> h (bf16)
  gemm_k<1, 1><<<gE, tb, 0, stream>>>(eb, nullptr, W1aT_b, nullptr, NE,
                                      nullptr, nullptr, nullptr, bufP, h,
                                      ei, sflag, nullptr);
  // Sbar = segment-mean of h -> bufP (P dead)
  seg_mean_k<<<NN, tb, 0, stream>>>(h, rowptr, perm, bufP);
  // G3: M = Sbar @ W1b + mask*b1b -> bufM (bf16)
  gemm_k<2, 1><<<gN, tb, 0, stream>>>(bufP, nullptr, W1bT, nullptr, NN,
                                      b1b, nullptr, bufM, nullptr, nullptr,
                                      nullptr, nullptr, cnt);
  // G4: out2 = relu(xb@W2a_top + M@W2a_bot + b2a) -> bufP (Sbar dead)
  gemm_k<3, 2><<<gN, tb, 0, stream>>>(xb, bufM, W2aT_t, W2aT_b, NN,
                                      b2a, nullptr, bufP, nullptr, nullptr,
                                      nullptr, nullptr, nullptr);
  // G5: out = out2 @ W2b + b2b -> d_out (fp32)
  gemm_k<0, 1><<<gN, tb, 0, stream>>>(bufP, nullptr, W2bT, nullptr, NN,
                                      b2b, out, nullptr, nullptr, nullptr,
                                      nullptr, nullptr, nullptr);
}